// Round 8
// baseline (631.325 us; speedup 1.0000x reference)
//
#include <hip/hip_runtime.h>
#include <hip/hip_bf16.h>

#define HW 65536
#define BATCH 4
#define NPIX (BATCH*HW)   // 262144 pixels

typedef unsigned short u16;
typedef unsigned int   u32;
typedef __attribute__((ext_vector_type(8))) short bh8;   // 8 bf16 (A/B frag, 4 VGPRs)
typedef __attribute__((ext_vector_type(4))) float f4;    // 4 f32 (C/D frag)

__device__ __forceinline__ float b2f(u16 u){
    u32 i = ((u32)u) << 16; float f; __builtin_memcpy(&f, &i, 4); return f;
}
__device__ __forceinline__ u16 f2b(float f){
    __hip_bfloat16 h = __float2bfloat16(f); u16 u; __builtin_memcpy(&u, &h, 2); return u;
}

__device__ __forceinline__ f4 mfma16(bh8 a, bh8 b, f4 c){
    return __builtin_amdgcn_mfma_f32_16x16x32_bf16(a, b, c, 0, 0, 0);
}

// ---------------- setup: weight cvt + LN rowsums + zero sums, one dispatch ----------------
struct CvtJob { const float* src; u16* dst; int n; const float* cs; };
struct SetupArgs {
    CvtJob j[12];
    const float* kvw[2]; const float* qw[2];
    const float* lnw; const float* lnb;
    float* sums; float* lnc;
};
__global__ __launch_bounds__(256) void setup_kernel(SetupArgs S){
    int blk = blockIdx.x;
    if (blk < 12){
        const CvtJob J = S.j[blk];
        if (J.cs){
            for (int i = threadIdx.x; i < J.n; i += 256) J.dst[i] = f2b(J.src[i] * J.cs[i & 63]);
        } else {
            for (int i = threadIdx.x; i < J.n; i += 256) J.dst[i] = f2b(J.src[i]);
        }
        return;
    }
    int pb = blk - 12;
    if (pb == 0){
        for (int i = threadIdx.x; i < 5120; i += 256) S.sums[i] = 0.f;
    } else {
        // lnc rowsums for merged gemm: seg = pb-1; rows 0-127 kv_w[seg], 128-191 q_w[1-seg]
        int seg = pb - 1;
        int o = threadIdx.x;
        if (o < 192){
            const float* W = (o < 128) ? S.kvw[seg] : S.qw[1-seg];
            int row = (o < 128) ? o : o - 128;
            float a = 0.f, bb = 0.f;
            for (int c = 0; c < 64; c++){
                float wv = W[row*64 + c];
                a = fmaf(wv, S.lnw[c], a); bb = fmaf(wv, S.lnb[c], bb);
            }
            S.lnc[seg*384 + o] = a; S.lnc[seg*384 + 192 + o] = bb;
        }
    }
}

// ---------------- merged LN-folded 1x1 conv GEMM: M=192 (kv + other-branch q) ----------------
struct GemmMerged {
    const float* in[2];
    const u16* wa[2];               // 192x64 bf16, pre-scaled by ln_w
    const float* rs[2]; const float* rb[2];   // 192 each
    u16* out0[2]; u16* out1[2]; u16* out2[2]; // kvLo, kvHi, q
};
__global__ __launch_bounds__(256) void gemmln_kernel(GemmMerged G){
    __shared__ u16 wl[192*64];
    int seg = blockIdx.x >> 10, tile = blockIdx.x & 1023;   // 1024 tiles/seg, 256 px each
    int w = threadIdx.x >> 6, lane = threadIdx.x & 63;
    int quad = lane >> 4, l16 = lane & 15;
    int b = tile >> 8;
    int pbase = ((tile & 255) << 8) + (w << 6) + (l16 << 2);  // 4 consecutive px/lane

    const float* in = G.in[seg];
    // all 16 channel-group loads in flight across weight staging + barrier
    f4 fin[8], fin2[8];
    #pragma unroll
    for (int j = 0; j < 8; j++)
        fin[j] = *(const f4*)(in + ((size_t)b*64 + quad*8 + j)*HW + pbase);
    #pragma unroll
    for (int j = 0; j < 8; j++)
        fin2[j] = *(const f4*)(in + ((size_t)b*64 + 32 + quad*8 + j)*HW + pbase);

    {
        const u16* W = G.wa[seg];
        for (int i = threadIdx.x; i < 192*8; i += 256){
            int row = i >> 3, ch = i & 7;
            uint4 v = *(const uint4*)(W + row*64 + ch*8);
            *(uint4*)(wl + row*64 + ((ch ^ (row & 7)) << 3)) = v;
        }
    }
    __syncthreads();

    // stats + bf16 fragments for both k-steps
    float s1[4] = {0.f,0.f,0.f,0.f}, s2[4] = {0.f,0.f,0.f,0.f};
    bh8 bfr[2][4];
    #pragma unroll
    for (int j = 0; j < 8; j++){
        f4 fv = fin[j];
        #pragma unroll
        for (int p = 0; p < 4; p++){
            float v = fv[p];
            s1[p] += v; s2[p] = fmaf(v, v, s2[p]);
            bfr[0][p][j] = (short)f2b(v);
        }
    }
    #pragma unroll
    for (int j = 0; j < 8; j++){
        f4 fv = fin2[j];
        #pragma unroll
        for (int p = 0; p < 4; p++){
            float v = fv[p];
            s1[p] += v; s2[p] = fmaf(v, v, s2[p]);
            bfr[1][p][j] = (short)f2b(v);
        }
    }

    float mu[4], iv[4];
    #pragma unroll
    for (int p = 0; p < 4; p++){
        s1[p] += __shfl_xor(s1[p], 16); s1[p] += __shfl_xor(s1[p], 32);
        s2[p] += __shfl_xor(s2[p], 16); s2[p] += __shfl_xor(s2[p], 32);
        mu[p] = s1[p]*(1.f/64.f);
        iv[p] = rsqrtf(s2[p]*(1.f/64.f) - mu[p]*mu[p] + 1e-5f);
    }

    const float* rs = G.rs[seg]; const float* rb = G.rb[seg];
    u16* o0 = G.out0[seg]; u16* o1 = G.out1[seg]; u16* o2 = G.out2[seg];
    #pragma unroll
    for (int mi = 0; mi < 12; mi++){
        f4 acc[4];
        #pragma unroll
        for (int p = 0; p < 4; p++) acc[p] = (f4){0.f,0.f,0.f,0.f};
        #pragma unroll
        for (int ks = 0; ks < 2; ks++){
            bh8 a;
            __builtin_memcpy(&a, wl + (mi*16 + l16)*64 + ((((ks<<2)+quad) ^ (l16 & 7)) << 3), 16);
            #pragma unroll
            for (int p = 0; p < 4; p++)
                acc[p] = mfma16(a, bfr[ks][p], acc[p]);
        }
        u16* dst = (mi < 4) ? o0 : (mi < 8) ? o1 : o2;
        #pragma unroll
        for (int r = 0; r < 4; r++){
            int o = mi*16 + quad*4 + r;
            size_t pidx = ((size_t)b*64 + (o & 63))*HW + pbase;
            float rsv = rs[o], rbv = rb[o];
            float v0 = iv[0]*(acc[0][r] - mu[0]*rsv) + rbv;
            float v1 = iv[1]*(acc[1][r] - mu[1]*rsv) + rbv;
            float v2 = iv[2]*(acc[2][r] - mu[2]*rsv) + rbv;
            float v3 = iv[3]*(acc[3][r] - mu[3]*rsv) + rbv;
            uint2 st;
            st.x = (u32)f2b(v0) | ((u32)f2b(v1) << 16);
            st.y = (u32)f2b(v2) | ((u32)f2b(v3) << 16);
            *(uint2*)(dst + pidx) = st;
        }
    }
}

// ---------------- depthwise 3x3, 6 planes in ONE dispatch, 8 px/thread ----------------
struct Dw6 { const u16* in[6]; u16* out[6]; const float* w[6]; int choff[6]; };
__global__ __launch_bounds__(256) void dw6_kernel(Dw6 A){
    int seg = blockIdx.x >> 13;                  // 6 segs x 8192 blocks
    int lid = ((blockIdx.x & 8191) << 8) + threadIdx.x;
    const u16* inp = A.in[seg];
    u16* outp      = A.out[seg];
    const float* wd = A.w[seg];
    int choff      = A.choff[seg];
    int bc = lid >> 13;
    int n8 = lid & 8191;
    int h = n8 >> 5, c8 = (n8 & 31) << 3;
    const float* wc = wd + ((size_t)((bc & 63) + choff))*9;
    const u16* p = inp + (size_t)bc*HW;
    float row[3][10];
    #pragma unroll
    for (int r = 0; r < 3; r++){
        int hh = h - 1 + r;
        bool ok = (unsigned)hh < 256u;
        const u16* pr = p + hh*256 + c8;
        if (ok){
            uint4 m = *(const uint4*)pr;
            row[r][1] = b2f((u16)m.x); row[r][2] = b2f((u16)(m.x>>16));
            row[r][3] = b2f((u16)m.y); row[r][4] = b2f((u16)(m.y>>16));
            row[r][5] = b2f((u16)m.z); row[r][6] = b2f((u16)(m.z>>16));
            row[r][7] = b2f((u16)m.w); row[r][8] = b2f((u16)(m.w>>16));
        } else {
            #pragma unroll
            for (int j = 1; j < 9; j++) row[r][j] = 0.f;
        }
        float lft = __shfl_up(row[r][8], 1);
        float rgt = __shfl_down(row[r][1], 1);
        row[r][0] = (c8 > 0)   ? lft : 0.f;
        row[r][9] = (c8 < 248) ? rgt : 0.f;
    }
    float o[8];
    #pragma unroll
    for (int i = 0; i < 8; i++){
        float a = 0.f;
        #pragma unroll
        for (int r = 0; r < 3; r++){
            a = fmaf(wc[r*3+0], row[r][i],   a);
            a = fmaf(wc[r*3+1], row[r][i+1], a);
            a = fmaf(wc[r*3+2], row[r][i+2], a);
        }
        o[i] = a;
    }
    uint4 st;
    st.x = (u32)f2b(o[0]) | ((u32)f2b(o[1])<<16);
    st.y = (u32)f2b(o[2]) | ((u32)f2b(o[3])<<16);
    st.z = (u32)f2b(o[4]) | ((u32)f2b(o[5])<<16);
    st.w = (u32)f2b(o[6]) | ((u32)f2b(o[7])<<16);
    *(uint4*)(outp + (size_t)bc*HW + h*256 + c8) = st;
}

// ---------------- attention partial sums (Gram + norms), dual-branch ----------------
#define NSL 64
struct AttnDual { const u16* q[2]; const u16* k[2]; float* sums; };
__global__ __launch_bounds__(256) void attn_part_kernel(AttnDual AD){
    int seg = blockIdx.x >> 11;
    int blk = blockIdx.x & 2047;     // B*8*NSL
    int sl = blk & (NSL-1);
    int bh = blk >> 6;               // b*8+h
    int b = bh >> 3, h = bh & 7;
    const u16* qp = AD.q[seg] + ((size_t)b*64 + h*8)*HW + sl*(HW/NSL);
    const u16* kp = AD.k[seg] + ((size_t)b*64 + h*8)*HW + sl*(HW/NSL);
    float acc[80];
    #pragma unroll
    for (int i = 0; i < 80; i++) acc[i] = 0.f;
    int n0 = threadIdx.x << 2;
    float qv[8][4], kw[8][4];
    #pragma unroll
    for (int i = 0; i < 8; i++){
        uint2 mq = *(const uint2*)(qp + (size_t)i*HW + n0);
        uint2 mk = *(const uint2*)(kp + (size_t)i*HW + n0);
        qv[i][0] = b2f((u16)(mq.x & 0xffffu)); qv[i][1] = b2f((u16)(mq.x >> 16));
        qv[i][2] = b2f((u16)(mq.y & 0xffffu)); qv[i][3] = b2f((u16)(mq.y >> 16));
        kw[i][0] = b2f((u16)(mk.x & 0xffffu)); kw[i][1] = b2f((u16)(mk.x >> 16));
        kw[i][2] = b2f((u16)(mk.y & 0xffffu)); kw[i][3] = b2f((u16)(mk.y >> 16));
    }
    #pragma unroll
    for (int i = 0; i < 8; i++){
        #pragma unroll
        for (int u = 0; u < 4; u++){
            acc[64+i] = fmaf(qv[i][u], qv[i][u], acc[64+i]);
            acc[72+i] = fmaf(kw[i][u], kw[i][u], acc[72+i]);
        }
        #pragma unroll
        for (int j = 0; j < 8; j++)
            #pragma unroll
            for (int u = 0; u < 4; u++)
                acc[i*8+j] = fmaf(qv[i][u], kw[j][u], acc[i*8+j]);
    }
    __shared__ float sred[4][80];
    int lane = threadIdx.x & 63, wv = threadIdx.x >> 6;
    #pragma unroll
    for (int t = 0; t < 80; t++){
        float r = acc[t];
        r += __shfl_down(r, 32); r += __shfl_down(r, 16); r += __shfl_down(r, 8);
        r += __shfl_down(r, 4);  r += __shfl_down(r, 2);  r += __shfl_down(r, 1);
        if (lane == 0) sred[wv][t] = r;
    }
    __syncthreads();
    if (threadIdx.x < 80){
        int t = threadIdx.x;
        atomicAdd(&AD.sums[seg*2560 + bh*80 + t], sred[0][t]+sred[1][t]+sred[2][t]+sred[3][t]);
    }
}

// ---------------- softmax + Weff = po . attn, dual-branch ----------------
struct WeffDual { const float* sums; const float* temp; const float* po[2]; u16* weff[2]; };
__global__ __launch_bounds__(64) void weff_kernel(WeffDual WD){
    int seg = blockIdx.x >> 2;
    int b = blockIdx.x & 3;
    const float* po = WD.po[seg];
    u16* weff = WD.weff[seg];
    __shared__ float at[8][8][8];
    int t = threadIdx.x;
    {
        int h = t >> 3, i = t & 7;
        const float* f = WD.sums + seg*2560 + (b*8 + h)*80;
        float iq = 1.f / fmaxf(sqrtf(f[64+i]), 1e-12f);
        float tv = WD.temp[h];
        float row[8]; float m = -1e30f;
        #pragma unroll
        for (int j = 0; j < 8; j++){
            float ik = 1.f / fmaxf(sqrtf(f[72+j]), 1e-12f);
            row[j] = f[i*8+j]*iq*ik*tv;
            m = fmaxf(m, row[j]);
        }
        float s = 0.f;
        #pragma unroll
        for (int j = 0; j < 8; j++){ row[j] = expf(row[j]-m); s += row[j]; }
        float rsv = 1.f/s;
        #pragma unroll
        for (int j = 0; j < 8; j++) at[h][i][j] = row[j]*rsv;
    }
    __syncthreads();
    int o = t;
    for (int g = 0; g < 64; g++){
        int h = g >> 3, j = g & 7;
        float wv = 0.f;
        #pragma unroll
        for (int i = 0; i < 8; i++) wv = fmaf(po[o*64 + h*8 + i], at[h][i][j], wv);
        weff[b*4096 + o*64 + g] = f2b(wv);
    }
}

// ---------------- fused modulation + final GEMM: 5-phase, 32 KB LDS, low-VGPR ----------------
// Phases: 1a(m1pre->LDS) | read m1frags | 1b(m2pre->LDS)+2a(s->bf16 regs) |
//         read m2frags+v | 2b(t, v'=v(s+1)+t ->LDS) | 3(Weff.v'+resid).
// s packed to bf16 in regs (spk) - one extra activation rounding.
struct ModFinal {
    const float* in[2]; const u16* wa[2]; const u16* wb[2];
    const float* b0[2]; const float* b2[2]; const float* b1[2]; const float* b3[2];
    const u16* wf[2];
    const u16* v[2];
    const float* resid[2];
    float* out[2];
};
__global__ __launch_bounds__(256,4) void modfinal_kernel(ModFinal M){
    __shared__ u32 lds[64*128];     // 64 rows x 256 px bf16 = 32 KB
    int seg = blockIdx.x >> 10, tile = blockIdx.x & 1023;
    int w = threadIdx.x >> 6, lane = threadIdx.x & 63;
    int quad = lane >> 4, l16 = lane & 15;
    int b = tile >> 8;
    int pbase = ((tile & 255) << 8) + (w << 6) + (l16 << 2);  // 4 px/lane
    int pp = ((w << 4) + l16) << 1;                           // u32-pair base in 128-wide row

    const float* in = M.in[seg];
    const u16* wa = M.wa[seg];
    const u16* wb = M.wb[seg];

    // ---- input load + convert (bfr = x in bf16, lives through stage 1b) ----
    bh8 bfr[2][4];
    {
        f4 fin[8];
        #pragma unroll
        for (int j = 0; j < 8; j++)
            fin[j] = *(const f4*)(in + ((size_t)b*64 + quad*8 + j)*HW + pbase);
        #pragma unroll
        for (int j = 0; j < 8; j++)
            #pragma unroll
            for (int p = 0; p < 4; p++) bfr[0][p][j] = (short)f2b(fin[j][p]);
        #pragma unroll
        for (int j = 0; j < 8; j++)
            fin[j] = *(const f4*)(in + ((size_t)b*64 + 32 + quad*8 + j)*HW + pbase);
        #pragma unroll
        for (int j = 0; j < 8; j++)
            #pragma unroll
            for (int p = 0; p < 4; p++) bfr[1][p][j] = (short)f2b(fin[j][p]);
    }

    // ---- stage 1a: m1pre (W0 rows 0-63) -> LDS, per-mi acc ----
    {
        const float* b0v = M.b0[seg];
        #pragma unroll
        for (int mi = 0; mi < 4; mi++){
            f4 acc[4];
            #pragma unroll
            for (int p = 0; p < 4; p++) acc[p] = (f4){0.f,0.f,0.f,0.f};
            #pragma unroll
            for (int ks = 0; ks < 2; ks++){
                bh8 a;
                __builtin_memcpy(&a, wa + (mi*16 + l16)*64 + ks*32 + quad*8, 16);
                #pragma unroll
                for (int p = 0; p < 4; p++) acc[p] = mfma16(a, bfr[ks][p], acc[p]);
            }
            #pragma unroll
            for (int r = 0; r < 4; r++){
                int o = mi*16 + quad*4 + r;
                float bi = b0v[o];
                float v0 = acc[0][r] + bi; v0 = v0 > 0.f ? v0 : 0.1f*v0;
                float v1 = acc[1][r] + bi; v1 = v1 > 0.f ? v1 : 0.1f*v1;
                float v2 = acc[2][r] + bi; v2 = v2 > 0.f ? v2 : 0.1f*v2;
                float v3 = acc[3][r] + bi; v3 = v3 > 0.f ? v3 : 0.1f*v3;
                uint2 st;
                st.x = (u32)f2b(v0) | ((u32)f2b(v1) << 16);
                st.y = (u32)f2b(v2) | ((u32)f2b(v3) << 16);
                *(uint2*)&lds[o*128 + ((pp + ((o>>2)&3)*8) & 127)] = st;
            }
        }
    }
    __syncthreads();

    // ---- read m1pre B-frags ----
    bh8 bsr[2][4];
    #pragma unroll
    for (int ks = 0; ks < 2; ks++){
        int kb = ks*32 + quad*8;
        #pragma unroll
        for (int j = 0; j < 8; j++){
            int ch = kb + j;
            uint2 m = *(const uint2*)&lds[ch*128 + ((pp + ((ch>>2)&3)*8) & 127)];
            bsr[ks][0][j] = (short)(m.x & 0xffffu);
            bsr[ks][1][j] = (short)(m.x >> 16);
            bsr[ks][2][j] = (short)(m.y & 0xffffu);
            bsr[ks][3][j] = (short)(m.y >> 16);
        }
    }
    __syncthreads();

    // ---- stage 1b: m2pre (W2 rows 64-127 of wa) -> LDS rows 0-63 (frees bfr) ----
    {
        const float* b2v = M.b2[seg];
        #pragma unroll
        for (int mi = 0; mi < 4; mi++){
            f4 acc[4];
            #pragma unroll
            for (int p = 0; p < 4; p++) acc[p] = (f4){0.f,0.f,0.f,0.f};
            #pragma unroll
            for (int ks = 0; ks < 2; ks++){
                bh8 a;
                __builtin_memcpy(&a, wa + ((64 + mi*16 + l16))*64 + ks*32 + quad*8, 16);
                #pragma unroll
                for (int p = 0; p < 4; p++) acc[p] = mfma16(a, bfr[ks][p], acc[p]);
            }
            #pragma unroll
            for (int r = 0; r < 4; r++){
                int o = mi*16 + quad*4 + r;
                float bi = b2v[o];
                float v0 = acc[0][r] + bi; v0 = v0 > 0.f ? v0 : 0.1f*v0;
                float v1 = acc[1][r] + bi; v1 = v1 > 0.f ? v1 : 0.1f*v1;
                float v2 = acc[2][r] + bi; v2 = v2 > 0.f ? v2 : 0.1f*v2;
                float v3 = acc[3][r] + bi; v3 = v3 > 0.f ? v3 : 0.1f*v3;
                uint2 st;
                st.x = (u32)f2b(v0) | ((u32)f2b(v1) << 16);
                st.y = (u32)f2b(v2) | ((u32)f2b(v3) << 16);
                *(uint2*)&lds[o*128 + ((pp + ((o>>2)&3)*8) & 127)] = st;
            }
        }
    }

    // ---- stage 2a: s = W1 . m1pre (from bsr regs) + b1, pack to bf16 regs ----
    uint2 spk[4][4];
    {
        const float* b1v = M.b1[seg];
        #pragma unroll
        for (int mi = 0; mi < 4; mi++){
            f4 acc[4];
            #pragma unroll
            for (int p = 0; p < 4; p++) acc[p] = (f4){0.f,0.f,0.f,0.f};
            #pragma unroll
            for (int ks = 0; ks < 2; ks++){
                bh8 a;
                __builtin_memcpy(&a, wb + (mi*16 + l16)*64 + ks*32 + quad*8, 16);
                #pragma unroll
                for (int p = 0; p < 4; p++) acc[p] = mfma16(a, bsr[ks][p], acc[p]);
            }
            #pragma unroll
            for (int r = 0; r < 4; r++){
                int o = mi*16 + quad*4 + r;
                float bi = b1v[o];
                uint2 st;
                st.x = (u32)f2b(acc[0][r] + bi) | ((u32)f2b(acc[1][r] + bi) << 16);
                st.y = (u32)f2b(acc[2][r] + bi) | ((u32)f2b(acc[3][r] + bi) << 16);
                spk[mi][r] = st;
            }
        }
    }
    __syncthreads();

    // ---- read m2pre B-frags + v prefetch ----
    bh8 btr[2][4];
    #pragma unroll
    for (int ks = 0; ks < 2; ks++){
        int kb = ks*32 + quad*8;
        #pragma unroll
        for (int j = 0; j < 8; j++){
            int ch = kb + j;
            uint2 m = *(const uint2*)&lds[ch*128 + ((pp + ((ch>>2)&3)*8) & 127)];
            btr[ks][0][j] = (short)(m.x & 0xffffu);
            btr[ks][1][j] = (short)(m.x >> 16);
            btr[ks][2][j] = (short)(m.y & 0xffffu);
            btr[ks][3][j] = (short)(m.y >> 16);
        }
    }
    uint2 vpref[16];
    {
        const u16* vP = M.v[seg];
        #pragma unroll
        for (int mi = 0; mi < 4; mi++)
        #pragma unroll
        for (int r = 0; r < 4; r++)
            vpref[mi*4+r] = *(const uint2*)(vP + ((size_t)b*64 + mi*16 + quad*4 + r)*HW + pbase);
    }
    __syncthreads();

    // ---- stage 2b: t = W3 . m2pre + b3; v' = v*(s+1)+t -> LDS ----
    {
        const float* b3v = M.b3[seg];
        #pragma unroll
        for (int mi = 0; mi < 4; mi++){
            f4 acc[4];
            #pragma unroll
            for (int p = 0; p < 4; p++) acc[p] = (f4){0.f,0.f,0.f,0.f};
            #pragma unroll
            for (int ks = 0; ks < 2; ks++){
                bh8 a;
                __builtin_memcpy(&a, wb + ((64 + mi*16 + l16))*64 + ks*32 + quad*8, 16);
                #pragma unroll
                for (int p = 0; p < 4; p++) acc[p] = mfma16(a, btr[ks][p], acc[p]);
            }
            #pragma unroll
            for (int r = 0; r < 4; r++){
                int o = mi*16 + quad*4 + r;
                float bi = b3v[o];
                uint2 sv = spk[mi][r];
                uint2 vv = vpref[mi*4+r];
                float s0 = b2f((u16)(sv.x & 0xffffu)), s1 = b2f((u16)(sv.x >> 16));
                float s2 = b2f((u16)(sv.y & 0xffffu)), s3 = b2f((u16)(sv.y >> 16));
                float va0 = b2f((u16)(vv.x & 0xffffu)), va1 = b2f((u16)(vv.x >> 16));
                float va2 = b2f((u16)(vv.y & 0xffffu)), va3 = b2f((u16)(vv.y >> 16));
                float o0 = va0*(s0+1.f) + (acc[0][r] + bi);
                float o1 = va1*(s1+1.f) + (acc[1][r] + bi);
                float o2 = va2*(s2+1.f) + (acc[2][r] + bi);
                float o3 = va3*(s3+1.f) + (acc[3][r] + bi);
                uint2 st;
                st.x = (u32)f2b(o0) | ((u32)f2b(o1) << 16);
                st.y = (u32)f2b(o2) | ((u32)f2b(o3) << 16);
                *(uint2*)&lds[o*128 + ((pp + ((o>>2)&3)*8) & 127)] = st;
            }
        }
    }
    __syncthreads();

    // ---- stage 3: out = Weff . v' + resid ----
    {
        const float* resid = M.resid[seg];
        float* outF = M.out[seg];
        const u16* wf = M.wf[seg] + b*4096;
        // resid prefetch in flight during LDS reads + MFMAs
        f4 rpre[16];
        #pragma unroll
        for (int mi = 0; mi < 4; mi++)
        #pragma unroll
        for (int r = 0; r < 4; r++)
            rpre[mi*4+r] = *(const f4*)(resid + ((size_t)b*64 + mi*16 + quad*4 + r)*HW + pbase);

        bh8 b3r[2][4];
        #pragma unroll
        for (int ks = 0; ks < 2; ks++){
            int kb = ks*32 + quad*8;
            #pragma unroll
            for (int j = 0; j < 8; j++){
                int ch = kb + j;
                uint2 m = *(const uint2*)&lds[ch*128 + ((pp + ((ch>>2)&3)*8) & 127)];
                b3r[ks][0][j] = (short)(m.x & 0xffffu);
                b3r[ks][1][j] = (short)(m.x >> 16);
                b3r[ks][2][j] = (short)(m.y & 0xffffu);
                b3r[ks][3][j] = (short)(m.y >> 16);
            }
        }
        #pragma unroll
        for (int mi = 0; mi < 4; mi++){
            f4 acc[4];
            #pragma unroll
            for (int p = 0; p < 4; p++) acc[p] = (f4){0.f,0.f,0.f,0.f};
            #pragma unroll
            for (int ks = 0; ks < 2; ks++){
                bh8 a;
                __builtin_memcpy(&a, wf + (mi*16 + l16)*64 + ks*32 + quad*8, 16);
                #pragma unroll
                for (int p = 0; p < 4; p++) acc[p] = mfma16(a, b3r[ks][p], acc[p]);
            }
            #pragma unroll
            for (int r = 0; r < 4; r++){
                int o = mi*16 + quad*4 + r;
                size_t pidx = ((size_t)b*64 + o)*HW + pbase;
                f4 rr = rpre[mi*4+r];
                f4 st;
                #pragma unroll
                for (int p = 0; p < 4; p++) st[p] = acc[p][r] + rr[p];
                *(f4*)(outF + pidx) = st;
            }
        }
    }
}

extern "C" void kernel_launch(void* const* d_in, const int* in_sizes, int n_in,
                              void* d_out, int out_size, void* d_ws, size_t ws_size,
                              hipStream_t stream){
    const float* x    = (const float*)d_in[0];
    const float* y    = (const float*)d_in[1];
    const float* ln_w = (const float*)d_in[2];
    const float* ln_b = (const float*)d_in[3];
    const float* temp = (const float*)d_in[4];
    const float* kv_w[2]   = {(const float*)d_in[5],  (const float*)d_in[10]};
    const float* kvdw_w[2] = {(const float*)d_in[6],  (const float*)d_in[11]};
    const float* q_w[2]    = {(const float*)d_in[7],  (const float*)d_in[12]};
    const float* qdw_w[2]  = {(const float*)d_in[8],  (const float*)d_in[13]};
    const float* po_w[2]   = {(const float*)d_in[9],  (const float*)d_in[14]};
    const float* mm_w[2]   = {(const float*)d_in[15], (const float*)d_in[17]};
    const float* mm_b[2]   = {(const float*)d_in[16], (const float*)d_in[18]};

    const size_t HPE = (size_t)BATCH*64*HW;   // elems per 64-ch plane
    u16* PL = (u16*)d_ws;                     // 12 planes
    u16* P[12];
    for (int i = 0; i < 12; i++) P[i] = PL + (size_t)i*HPE;
    float* sums = (float*)(PL + 12*HPE);      // 2 * 2560 f32
    float* lnc  = sums + 5120;                // 768 f32 LN rowsum constants
    u16* warena = (u16*)(lnc + 768);
    // merged gemm arenas: seg0 = kv_w[0](8192) + q_w[1](4096); seg1 = kv_w[1] + q_w[0]
    const int WG[2] = {0, 12288};
    const int WMA[2] = {24576, 40960}, WMB[2] = {32768, 49152};
    const int WEFF[2] = {57344, 73728};

    size_t need = 12*HPE*2 + (5120+768)*4 + 90112*2;
    if (ws_size < need) return;

    SetupArgs S{};
    int nj = 0;
    auto add = [&](const float* s, u16* d, int n, const float* cs){ S.j[nj] = {s, d, n, cs}; nj++; };
    add(kv_w[0], warena + WG[0],        8192, ln_w);
    add(q_w[1],  warena + WG[0] + 8192, 4096, ln_w);
    add(kv_w[1], warena + WG[1],        8192, ln_w);
    add(q_w[0],  warena + WG[1] + 8192, 4096, ln_w);
    for (int br = 0; br < 2; br++){
        add(mm_w[br],        warena + WMA[br],        4096, nullptr);  // W0 -> rows 0-63
        add(mm_w[br]+8192,   warena + WMA[br] + 4096, 4096, nullptr);  // W2 -> rows 64-127
        add(mm_w[br]+4096,   warena + WMB[br],        4096, nullptr);  // W1 -> rows 0-63
        add(mm_w[br]+12288,  warena + WMB[br] + 4096, 4096, nullptr);  // W3 -> rows 64-127
    }
    S.kvw[0] = kv_w[0]; S.kvw[1] = kv_w[1];
    S.qw[0]  = q_w[0];  S.qw[1]  = q_w[1];
    S.lnw = ln_w; S.lnb = ln_b; S.sums = sums; S.lnc = lnc;
    setup_kernel<<<15, 256, 0, stream>>>(S);

    const int GT = NPIX/256;     // 1024 gemm tiles per seg (256 px each)

    // merged LN-GEMM: seg0 x -> P0(k0),P1(v0),P5(q1); seg1 y -> P2(k1),P3(v1),P4(q0)
    GemmMerged GK{};
    GK.in[0] = x; GK.in[1] = y;
    GK.wa[0] = warena + WG[0]; GK.wa[1] = warena + WG[1];
    GK.rs[0] = lnc;        GK.rb[0] = lnc + 192;
    GK.rs[1] = lnc + 384;  GK.rb[1] = lnc + 576;
    GK.out0[0] = P[0]; GK.out1[0] = P[1]; GK.out2[0] = P[5];
    GK.out0[1] = P[2]; GK.out1[1] = P[3]; GK.out2[1] = P[4];
    gemmln_kernel<<<2*GT, 256, 0, stream>>>(GK);

    // depthwise, all 6 planes in one dispatch:
    // br0: P0->P6 (k), P1->P7 (v), P4->P8 (q); br1: P2->P9, P3->P10, P5->P11
    Dw6 D{};
    D.in[0] = P[0];  D.out[0] = P[6];  D.w[0] = kvdw_w[0]; D.choff[0] = 0;
    D.in[1] = P[1];  D.out[1] = P[7];  D.w[1] = kvdw_w[0]; D.choff[1] = 64;
    D.in[2] = P[4];  D.out[2] = P[8];  D.w[2] = qdw_w[0];  D.choff[2] = 0;
    D.in[3] = P[2];  D.out[3] = P[9];  D.w[3] = kvdw_w[1]; D.choff[3] = 0;
    D.in[4] = P[3];  D.out[4] = P[10]; D.w[4] = kvdw_w[1]; D.choff[4] = 64;
    D.in[5] = P[5];  D.out[5] = P[11]; D.w[5] = qdw_w[1];  D.choff[5] = 0;
    dw6_kernel<<<6*8192, 256, 0, stream>>>(D);

    // attention stats both branches
    AttnDual AD{};
    AD.q[0] = P[8];  AD.k[0] = P[6];
    AD.q[1] = P[11]; AD.k[1] = P[9];
    AD.sums = sums;
    attn_part_kernel<<<2*BATCH*8*NSL, 256, 0, stream>>>(AD);

    // softmax + Weff both branches
    WeffDual WD{};
    WD.sums = sums; WD.temp = temp;
    WD.po[0] = po_w[0]; WD.po[1] = po_w[1];
    WD.weff[0] = warena + WEFF[0]; WD.weff[1] = warena + WEFF[1];
    weff_kernel<<<2*BATCH, 64, 0, stream>>>(WD);

    // fused modulation + final both branches
    float* outp = (float*)d_out;
    ModFinal M{};
    M.in[0] = x; M.in[1] = y;
    M.wa[0] = warena + WMA[0]; M.wa[1] = warena + WMA[1];
    M.wb[0] = warena + WMB[0]; M.wb[1] = warena + WMB[1];
    M.b0[0] = mm_b[0];       M.b0[1] = mm_b[1];
    M.b2[0] = mm_b[0] + 128; M.b2[1] = mm_b[1] + 128;
    M.b1[0] = mm_b[0] + 64;  M.b1[1] = mm_b[1] + 64;
    M.b3[0] = mm_b[0] + 192; M.b3[1] = mm_b[1] + 192;
    M.wf[0] = warena + WEFF[0]; M.wf[1] = warena + WEFF[1];
    M.v[0] = P[7]; M.v[1] = P[10];
    M.resid[0] = y; M.resid[1] = x;
    M.out[0] = outp; M.out[1] = outp + HPE;
    modfinal_kernel<<<2*GT, 256, 0, stream>>>(M);
}

// Round 10
// 618.157 us; speedup vs baseline: 1.0213x; 1.0213x over previous
//
#include <hip/hip_runtime.h>
#include <hip/hip_bf16.h>

#define HW 65536
#define BATCH 4
#define NPIX (BATCH*HW)   // 262144 pixels

typedef unsigned short u16;
typedef unsigned int   u32;
typedef __attribute__((ext_vector_type(8))) short bh8;   // 8 bf16 (A/B frag, 4 VGPRs)
typedef __attribute__((ext_vector_type(4))) float f4;    // 4 f32 (C/D frag)

__device__ __forceinline__ float b2f(u16 u){
    u32 i = ((u32)u) << 16; float f; __builtin_memcpy(&f, &i, 4); return f;
}
__device__ __forceinline__ u16 f2b(float f){
    __hip_bfloat16 h = __float2bfloat16(f); u16 u; __builtin_memcpy(&u, &h, 2); return u;
}

__device__ __forceinline__ f4 mfma16(bh8 a, bh8 b, f4 c){
    return __builtin_amdgcn_mfma_f32_16x16x32_bf16(a, b, c, 0, 0, 0);
}

// ---------------- setup: weight cvt + LN rowsums + zero sums, one dispatch ----------------
struct CvtJob { const float* src; u16* dst; int n; const float* cs; };
struct SetupArgs {
    CvtJob j[12];
    const float* kvw[2]; const float* qw[2];
    const float* lnw; const float* lnb;
    float* sums; float* lnc;
};
__global__ __launch_bounds__(256) void setup_kernel(SetupArgs S){
    int blk = blockIdx.x;
    if (blk < 12){
        const CvtJob J = S.j[blk];
        if (J.cs){
            for (int i = threadIdx.x; i < J.n; i += 256) J.dst[i] = f2b(J.src[i] * J.cs[i & 63]);
        } else {
            for (int i = threadIdx.x; i < J.n; i += 256) J.dst[i] = f2b(J.src[i]);
        }
        return;
    }
    int pb = blk - 12;
    if (pb == 0){
        for (int i = threadIdx.x; i < 5120; i += 256) S.sums[i] = 0.f;
    } else {
        // lnc rowsums for merged gemm: seg = pb-1; rows 0-127 kv_w[seg], 128-191 q_w[1-seg]
        int seg = pb - 1;
        int o = threadIdx.x;
        if (o < 192){
            const float* W = (o < 128) ? S.kvw[seg] : S.qw[1-seg];
            int row = (o < 128) ? o : o - 128;
            float a = 0.f, bb = 0.f;
            for (int c = 0; c < 64; c++){
                float wv = W[row*64 + c];
                a = fmaf(wv, S.lnw[c], a); bb = fmaf(wv, S.lnb[c], bb);
            }
            S.lnc[seg*384 + o] = a; S.lnc[seg*384 + 192 + o] = bb;
        }
    }
}

// ---------------- merged LN-folded 1x1 conv GEMM: M=192, LDS-staged coalesced input --------
// Staging: thread (ct=t>>6, pt=t&63) loads ch=c8*4+ct at px pt*4 -> each load
// instruction = 64 lanes x 16B contiguous in ONE channel row (1 KB). bf16 into
// swizzled LDS tile; f32 LN partials into 8 KB side array. Then B-frags from LDS.
struct GemmMerged {
    const float* in[2];
    const u16* wa[2];               // 192x64 bf16, pre-scaled by ln_w
    const float* rs[2]; const float* rb[2];   // 192 each
    u16* out0[2]; u16* out1[2]; u16* out2[2]; // kvLo, kvHi, q
};
__global__ __launch_bounds__(256,4) void gemmln_kernel(GemmMerged G){
    __shared__ u32 ti[64*128];       // 64 ch x 256 px bf16 (u32 pairs), 32 KB
    __shared__ float ts[8*256];      // [stat(2)][ct(4)][px(256)] partials, 8 KB
    int seg = blockIdx.x >> 10, tile = blockIdx.x & 1023;   // 1024 tiles/seg, 256 px each
    int b = tile >> 8;
    int PB = (tile & 255) << 8;                             // px base within batch

    const float* in = G.in[seg] + (size_t)b*64*HW + PB;

    // ---- staging: 16 x (1KB-contiguous load, convert, store) ----
    {
        int ct = threadIdx.x >> 6, pt = threadIdx.x & 63;
        f4 fin[16];
        #pragma unroll
        for (int c8 = 0; c8 < 16; c8++)
            fin[c8] = *(const f4*)(in + (size_t)(c8*4 + ct)*HW + pt*4);
        float s1p[4] = {0.f,0.f,0.f,0.f}, s2p[4] = {0.f,0.f,0.f,0.f};
        #pragma unroll
        for (int c8 = 0; c8 < 16; c8++){
            int ch = c8*4 + ct;
            f4 fv = fin[c8];
            uint2 st;
            st.x = (u32)f2b(fv[0]) | ((u32)f2b(fv[1]) << 16);
            st.y = (u32)f2b(fv[2]) | ((u32)f2b(fv[3]) << 16);
            *(uint2*)&ti[ch*128 + ((2*pt + ((ch>>2)&3)*8) & 127)] = st;
            #pragma unroll
            for (int p = 0; p < 4; p++){
                s1p[p] += fv[p];
                s2p[p] = fmaf(fv[p], fv[p], s2p[p]);
            }
        }
        #pragma unroll
        for (int p = 0; p < 4; p++){
            ts[(0*4 + ct)*256 + pt*4 + p] = s1p[p];
            ts[(1*4 + ct)*256 + pt*4 + p] = s2p[p];
        }
    }
    __syncthreads();

    int w = threadIdx.x >> 6, lane = threadIdx.x & 63;
    int quad = lane >> 4, l16 = lane & 15;
    int gp = w*16 + l16;                     // px-quad group (4 px each)
    int pbase = PB + gp*4;                   // px within batch (for stores)

    // ---- B-frags from LDS ----
    bh8 bfr[2][4];
    #pragma unroll
    for (int ks = 0; ks < 2; ks++){
        #pragma unroll
        for (int j = 0; j < 8; j++){
            int ch = ks*32 + quad*8 + j;
            uint2 m = *(const uint2*)&ti[ch*128 + ((2*gp + ((ch>>2)&3)*8) & 127)];
            bfr[ks][0][j] = (short)(m.x & 0xffffu);
            bfr[ks][1][j] = (short)(m.x >> 16);
            bfr[ks][2][j] = (short)(m.y & 0xffffu);
            bfr[ks][3][j] = (short)(m.y >> 16);
        }
    }
    // ---- LN stats from partials (f32 exact) ----
    float mu[4], iv[4];
    #pragma unroll
    for (int p = 0; p < 4; p++){
        int px = gp*4 + p;
        float s1 = ts[0*256 + px] + ts[1*256 + px] + ts[2*256 + px] + ts[3*256 + px];
        float s2 = ts[(4+0)*256 + px] + ts[(4+1)*256 + px] + ts[(4+2)*256 + px] + ts[(4+3)*256 + px];
        mu[p] = s1*(1.f/64.f);
        iv[p] = rsqrtf(s2*(1.f/64.f) - mu[p]*mu[p] + 1e-5f);
    }

    const u16* W = G.wa[seg];
    const float* rs = G.rs[seg]; const float* rb = G.rb[seg];
    u16* o0 = G.out0[seg]; u16* o1 = G.out1[seg]; u16* o2 = G.out2[seg];
    #pragma unroll
    for (int mi = 0; mi < 12; mi++){
        f4 acc[4];
        #pragma unroll
        for (int p = 0; p < 4; p++) acc[p] = (f4){0.f,0.f,0.f,0.f};
        #pragma unroll
        for (int ks = 0; ks < 2; ks++){
            bh8 a;
            __builtin_memcpy(&a, W + (mi*16 + l16)*64 + ks*32 + quad*8, 16);
            #pragma unroll
            for (int p = 0; p < 4; p++)
                acc[p] = mfma16(a, bfr[ks][p], acc[p]);
        }
        u16* dst = (mi < 4) ? o0 : (mi < 8) ? o1 : o2;
        #pragma unroll
        for (int r = 0; r < 4; r++){
            int o = mi*16 + quad*4 + r;
            size_t pidx = ((size_t)b*64 + (o & 63))*HW + pbase;
            float rsv = rs[o], rbv = rb[o];
            float v0 = iv[0]*(acc[0][r] - mu[0]*rsv) + rbv;
            float v1 = iv[1]*(acc[1][r] - mu[1]*rsv) + rbv;
            float v2 = iv[2]*(acc[2][r] - mu[2]*rsv) + rbv;
            float v3 = iv[3]*(acc[3][r] - mu[3]*rsv) + rbv;
            uint2 st;
            st.x = (u32)f2b(v0) | ((u32)f2b(v1) << 16);
            st.y = (u32)f2b(v2) | ((u32)f2b(v3) << 16);
            *(uint2*)(dst + pidx) = st;
        }
    }
}

// ---------------- depthwise 3x3, 6 planes in ONE dispatch, 8 px/thread ----------------
struct Dw6 { const u16* in[6]; u16* out[6]; const float* w[6]; int choff[6]; };
__global__ __launch_bounds__(256) void dw6_kernel(Dw6 A){
    int seg = blockIdx.x >> 13;                  // 6 segs x 8192 blocks
    int lid = ((blockIdx.x & 8191) << 8) + threadIdx.x;
    const u16* inp = A.in[seg];
    u16* outp      = A.out[seg];
    const float* wd = A.w[seg];
    int choff      = A.choff[seg];
    int bc = lid >> 13;
    int n8 = lid & 8191;
    int h = n8 >> 5, c8 = (n8 & 31) << 3;
    const float* wc = wd + ((size_t)((bc & 63) + choff))*9;
    const u16* p = inp + (size_t)bc*HW;
    float row[3][10];
    #pragma unroll
    for (int r = 0; r < 3; r++){
        int hh = h - 1 + r;
        bool ok = (unsigned)hh < 256u;
        const u16* pr = p + hh*256 + c8;
        if (ok){
            uint4 m = *(const uint4*)pr;
            row[r][1] = b2f((u16)m.x); row[r][2] = b2f((u16)(m.x>>16));
            row[r][3] = b2f((u16)m.y); row[r][4] = b2f((u16)(m.y>>16));
            row[r][5] = b2f((u16)m.z); row[r][6] = b2f((u16)(m.z>>16));
            row[r][7] = b2f((u16)m.w); row[r][8] = b2f((u16)(m.w>>16));
        } else {
            #pragma unroll
            for (int j = 1; j < 9; j++) row[r][j] = 0.f;
        }
        float lft = __shfl_up(row[r][8], 1);
        float rgt = __shfl_down(row[r][1], 1);
        row[r][0] = (c8 > 0)   ? lft : 0.f;
        row[r][9] = (c8 < 248) ? rgt : 0.f;
    }
    float o[8];
    #pragma unroll
    for (int i = 0; i < 8; i++){
        float a = 0.f;
        #pragma unroll
        for (int r = 0; r < 3; r++){
            a = fmaf(wc[r*3+0], row[r][i],   a);
            a = fmaf(wc[r*3+1], row[r][i+1], a);
            a = fmaf(wc[r*3+2], row[r][i+2], a);
        }
        o[i] = a;
    }
    uint4 st;
    st.x = (u32)f2b(o[0]) | ((u32)f2b(o[1])<<16);
    st.y = (u32)f2b(o[2]) | ((u32)f2b(o[3])<<16);
    st.z = (u32)f2b(o[4]) | ((u32)f2b(o[5])<<16);
    st.w = (u32)f2b(o[6]) | ((u32)f2b(o[7])<<16);
    *(uint4*)(outp + (size_t)bc*HW + h*256 + c8) = st;
}

// ---------------- attention partial sums (Gram + norms), dual-branch ----------------
#define NSL 64
struct AttnDual { const u16* q[2]; const u16* k[2]; float* sums; };
__global__ __launch_bounds__(256) void attn_part_kernel(AttnDual AD){
    int seg = blockIdx.x >> 11;
    int blk = blockIdx.x & 2047;     // B*8*NSL
    int sl = blk & (NSL-1);
    int bh = blk >> 6;               // b*8+h
    int b = bh >> 3, h = bh & 7;
    const u16* qp = AD.q[seg] + ((size_t)b*64 + h*8)*HW + sl*(HW/NSL);
    const u16* kp = AD.k[seg] + ((size_t)b*64 + h*8)*HW + sl*(HW/NSL);
    float acc[80];
    #pragma unroll
    for (int i = 0; i < 80; i++) acc[i] = 0.f;
    int n0 = threadIdx.x << 2;
    float qv[8][4], kw[8][4];
    #pragma unroll
    for (int i = 0; i < 8; i++){
        uint2 mq = *(const uint2*)(qp + (size_t)i*HW + n0);
        uint2 mk = *(const uint2*)(kp + (size_t)i*HW + n0);
        qv[i][0] = b2f((u16)(mq.x & 0xffffu)); qv[i][1] = b2f((u16)(mq.x >> 16));
        qv[i][2] = b2f((u16)(mq.y & 0xffffu)); qv[i][3] = b2f((u16)(mq.y >> 16));
        kw[i][0] = b2f((u16)(mk.x & 0xffffu)); kw[i][1] = b2f((u16)(mk.x >> 16));
        kw[i][2] = b2f((u16)(mk.y & 0xffffu)); kw[i][3] = b2f((u16)(mk.y >> 16));
    }
    #pragma unroll
    for (int i = 0; i < 8; i++){
        #pragma unroll
        for (int u = 0; u < 4; u++){
            acc[64+i] = fmaf(qv[i][u], qv[i][u], acc[64+i]);
            acc[72+i] = fmaf(kw[i][u], kw[i][u], acc[72+i]);
        }
        #pragma unroll
        for (int j = 0; j < 8; j++)
            #pragma unroll
            for (int u = 0; u < 4; u++)
                acc[i*8+j] = fmaf(qv[i][u], kw[j][u], acc[i*8+j]);
    }
    __shared__ float sred[4][80];
    int lane = threadIdx.x & 63, wv = threadIdx.x >> 6;
    #pragma unroll
    for (int t = 0; t < 80; t++){
        float r = acc[t];
        r += __shfl_down(r, 32); r += __shfl_down(r, 16); r += __shfl_down(r, 8);
        r += __shfl_down(r, 4);  r += __shfl_down(r, 2);  r += __shfl_down(r, 1);
        if (lane == 0) sred[wv][t] = r;
    }
    __syncthreads();
    if (threadIdx.x < 80){
        int t = threadIdx.x;
        atomicAdd(&AD.sums[seg*2560 + bh*80 + t], sred[0][t]+sred[1][t]+sred[2][t]+sred[3][t]);
    }
}

// ---------------- softmax + Weff = po . attn, dual-branch ----------------
struct WeffDual { const float* sums; const float* temp; const float* po[2]; u16* weff[2]; };
__global__ __launch_bounds__(64) void weff_kernel(WeffDual WD){
    int seg = blockIdx.x >> 2;
    int b = blockIdx.x & 3;
    const float* po = WD.po[seg];
    u16* weff = WD.weff[seg];
    __shared__ float at[8][8][8];
    int t = threadIdx.x;
    {
        int h = t >> 3, i = t & 7;
        const float* f = WD.sums + seg*2560 + (b*8 + h)*80;
        float iq = 1.f / fmaxf(sqrtf(f[64+i]), 1e-12f);
        float tv = WD.temp[h];
        float row[8]; float m = -1e30f;
        #pragma unroll
        for (int j = 0; j < 8; j++){
            float ik = 1.f / fmaxf(sqrtf(f[72+j]), 1e-12f);
            row[j] = f[i*8+j]*iq*ik*tv;
            m = fmaxf(m, row[j]);
        }
        float s = 0.f;
        #pragma unroll
        for (int j = 0; j < 8; j++){ row[j] = expf(row[j]-m); s += row[j]; }
        float rsv = 1.f/s;
        #pragma unroll
        for (int j = 0; j < 8; j++) at[h][i][j] = row[j]*rsv;
    }
    __syncthreads();
    int o = t;
    for (int g = 0; g < 64; g++){
        int h = g >> 3, j = g & 7;
        float wv = 0.f;
        #pragma unroll
        for (int i = 0; i < 8; i++) wv = fmaf(po[o*64 + h*8 + i], at[h][i][j], wv);
        weff[b*4096 + o*64 + g] = f2b(wv);
    }
}

// ---------------- fused modulation + final GEMM, dual-branch, 4 px/lane ----------------
// (round-7 structure: 64 KB LDS, 3-stage, v/resid prefetch)
struct ModFinal {
    const float* in[2]; const u16* wa[2]; const u16* wb[2];
    const float* b0[2]; const float* b2[2]; const float* b1[2]; const float* b3[2];
    const u16* wf[2];
    const u16* v[2];
    const float* resid[2];
    float* out[2];
};
__global__ __launch_bounds__(256) void modfinal_kernel(ModFinal M){
    __shared__ u32 lds[128*128];
    int seg = blockIdx.x >> 10, tile = blockIdx.x & 1023;
    int w = threadIdx.x >> 6, lane = threadIdx.x & 63;
    int quad = lane >> 4, l16 = lane & 15;
    int b = tile >> 8;
    int pbase = ((tile & 255) << 8) + (w << 6) + (l16 << 2);  // 4 px/lane
    int pp = ((w << 4) + l16) << 1;                           // u32-pair base in 128-wide row

    const float* in = M.in[seg];
    const u16* wa = M.wa[seg];

    // ---- stage 1: all 16 channel loads in flight ----
    f4 fin[8], fin2[8];
    #pragma unroll
    for (int j = 0; j < 8; j++)
        fin[j] = *(const f4*)(in + ((size_t)b*64 + quad*8 + j)*HW + pbase);
    #pragma unroll
    for (int j = 0; j < 8; j++)
        fin2[j] = *(const f4*)(in + ((size_t)b*64 + 32 + quad*8 + j)*HW + pbase);

    f4 acc[8][4];
    #pragma unroll
    for (int mi = 0; mi < 8; mi++)
        #pragma unroll
        for (int p = 0; p < 4; p++) acc[mi][p] = (f4){0.f,0.f,0.f,0.f};

    #pragma unroll
    for (int ks = 0; ks < 2; ks++){
        bh8 bfr[4];
        #pragma unroll
        for (int j = 0; j < 8; j++){
            f4 fv = (ks == 0) ? fin[j] : fin2[j];
            #pragma unroll
            for (int p = 0; p < 4; p++) bfr[p][j] = (short)f2b(fv[p]);
        }
        #pragma unroll
        for (int mi = 0; mi < 8; mi++){
            bh8 a;
            __builtin_memcpy(&a, wa + (mi*16 + l16)*64 + ks*32 + quad*8, 16);
            #pragma unroll
            for (int p = 0; p < 4; p++)
                acc[mi][p] = mfma16(a, bfr[p], acc[mi][p]);
        }
    }

    // ---- v prefetch (uint2 = 4 px bf16): hidden under epi + barrier + stage 2 ----
    uint2 vpref[16];
    {
        const u16* vP = M.v[seg];
        #pragma unroll
        for (int mi = 0; mi < 4; mi++)
        #pragma unroll
        for (int r = 0; r < 4; r++)
            vpref[mi*4+r] = *(const uint2*)(vP + ((size_t)b*64 + mi*16 + quad*4 + r)*HW + pbase);
    }

    // ---- stage-1 epilogue: bias + lrelu -> LDS ----
    {
        const float* b0v = M.b0[seg]; const float* b2v = M.b2[seg];
        #pragma unroll
        for (int mi = 0; mi < 8; mi++)
        #pragma unroll
        for (int r = 0; r < 4; r++){
            int o = mi*16 + quad*4 + r;
            float bi = (o < 64) ? b0v[o] : b2v[o-64];
            float v0 = acc[mi][0][r] + bi; v0 = v0 > 0.f ? v0 : 0.1f*v0;
            float v1 = acc[mi][1][r] + bi; v1 = v1 > 0.f ? v1 : 0.1f*v1;
            float v2 = acc[mi][2][r] + bi; v2 = v2 > 0.f ? v2 : 0.1f*v2;
            float v3 = acc[mi][3][r] + bi; v3 = v3 > 0.f ? v3 : 0.1f*v3;
            uint2 st;
            st.x = (u32)f2b(v0) | ((u32)f2b(v1) << 16);
            st.y = (u32)f2b(v2) | ((u32)f2b(v3) << 16);
            *(uint2*)&lds[o*128 + ((pp + ((o>>2)&3)*8) & 127)] = st;
        }
    }
    __syncthreads();

    // ---- stage 2 (block-diag K=128) ----
    const u16* wb = M.wb[seg];
    f4 acc2[8][4];
    #pragma unroll
    for (int mi = 0; mi < 8; mi++)
        #pragma unroll
        for (int p = 0; p < 4; p++) acc2[mi][p] = (f4){0.f,0.f,0.f,0.f};
    #pragma unroll
    for (int ks = 0; ks < 4; ks++){
        int kb = ks*32 + quad*8;
        bh8 bfr[4];
        #pragma unroll
        for (int j = 0; j < 8; j++){
            int ch = kb + j;
            uint2 m = *(const uint2*)&lds[ch*128 + ((pp + ((ch>>2)&3)*8) & 127)];
            bfr[0][j] = (short)(m.x & 0xffffu);
            bfr[1][j] = (short)(m.x >> 16);
            bfr[2][j] = (short)(m.y & 0xffffu);
            bfr[3][j] = (short)(m.y >> 16);
        }
        #pragma unroll
        for (int mi = 0; mi < 8; mi++){
            if (mi < 4 ? (ks < 2) : (ks >= 2)){
                int ksl = (mi >= 4) ? ks - 2 : ks;
                bh8 a;
                __builtin_memcpy(&a, wb + (mi*16 + l16)*64 + ksl*32 + quad*8, 16);
                #pragma unroll
                for (int p = 0; p < 4; p++)
                    acc2[mi][p] = mfma16(a, bfr[p], acc2[mi][p]);
            }
        }
    }
    __syncthreads();   // stage-2 reads done before v' overwrite

    // ---- vmod: v' = v*(s+1)+t -> LDS rows 0..63 ----
    {
        const float* b1v = M.b1[seg]; const float* b3v = M.b3[seg];
        #pragma unroll
        for (int mi = 0; mi < 4; mi++)
        #pragma unroll
        for (int r = 0; r < 4; r++){
            int o = mi*16 + quad*4 + r;
            uint2 vv = vpref[mi*4+r];
            float va[4] = { b2f((u16)(vv.x & 0xffffu)), b2f((u16)(vv.x >> 16)),
                            b2f((u16)(vv.y & 0xffffu)), b2f((u16)(vv.y >> 16)) };
            float ov[4];
            #pragma unroll
            for (int p = 0; p < 4; p++){
                float s = acc2[mi][p][r] + b1v[o];
                float t = acc2[mi+4][p][r] + b3v[o];
                ov[p] = va[p]*(s+1.f)+t;
            }
            uint2 st;
            st.x = (u32)f2b(ov[0]) | ((u32)f2b(ov[1]) << 16);
            st.y = (u32)f2b(ov[2]) | ((u32)f2b(ov[3]) << 16);
            *(uint2*)&lds[o*128 + ((pp + ((o>>2)&3)*8) & 127)] = st;
        }
    }
    // ---- resid prefetch (float4): hidden across barrier + stage 3 ----
    f4 rpre[16];
    {
        const float* resid = M.resid[seg];
        #pragma unroll
        for (int mi = 0; mi < 4; mi++)
        #pragma unroll
        for (int r = 0; r < 4; r++)
            rpre[mi*4+r] = *(const f4*)(resid + ((size_t)b*64 + mi*16 + quad*4 + r)*HW + pbase);
    }
    __syncthreads();

    // ---- stage 3: out = Weff . v' + resid ----
    const u16* wf = M.wf[seg] + b*4096;
    f4 accF[4][4];
    #pragma unroll
    for (int mi = 0; mi < 4; mi++)
        #pragma unroll
        for (int p = 0; p < 4; p++) accF[mi][p] = (f4){0.f,0.f,0.f,0.f};
    #pragma unroll
    for (int ks = 0; ks < 2; ks++){
        int kb = ks*32 + quad*8;
        bh8 bfr[4];
        #pragma unroll
        for (int j = 0; j < 8; j++){
            int ch = kb + j;
            uint2 m = *(const uint2*)&lds[ch*128 + ((pp + ((ch>>2)&3)*8) & 127)];
            bfr[0][j] = (short)(m.x & 0xffffu);
            bfr[1][j] = (short)(m.x >> 16);
            bfr[2][j] = (short)(m.y & 0xffffu);
            bfr[3][j] = (short)(m.y >> 16);
        }
        #pragma unroll
        for (int mi = 0; mi < 4; mi++){
            bh8 a;
            __builtin_memcpy(&a, wf + (mi*16 + l16)*64 + ks*32 + quad*8, 16);
            #pragma unroll
            for (int p = 0; p < 4; p++)
                accF[mi][p] = mfma16(a, bfr[p], accF[mi][p]);
        }
    }
    {
        float* outF = M.out[seg];
        #pragma unroll
        for (int mi = 0; mi < 4; mi++)
        #pragma unroll
        for (int r = 0; r < 4; r++){
            int o = mi*16 + quad*4 + r;
            size_t pidx = ((size_t)b*64 + o)*HW + pbase;
            f4 rr = rpre[mi*4+r];
            f4 st;
            #pragma unroll
            for (int p = 0; p < 4; p++) st[p] = accF[mi][p][r] + rr[p];
            *(f4*)(outF + pidx) = st;
        }
    }
}

extern "C" void kernel_launch(void* const* d_in, const int* in_sizes, int n_in,
                              void* d_out, int out_size, void* d_ws, size_t ws_size,
                              hipStream_t stream){
    const float* x    = (const float*)d_in[0];
    const float* y    = (const float*)d_in[1];
    const float* ln_w = (const float*)d_in[2];
    const float* ln_b = (const float*)d_in[3];
    const float* temp = (const float*)d_in[4];
    const float* kv_w[2]   = {(const float*)d_in[5],  (const float*)d_in[10]};
    const float* kvdw_w[2] = {(const float*)d_in[6],  (const float*)d_in[11]};
    const float* q_w[2]    = {(const float*)d_in[7],  (const float*)d_in[12]};
    const float* qdw_w[2]  = {(const float*)d_in[8],  (const float*)d_in[13]};
    const float* po_w[2]   = {(const float*)d_in[9],  (const float*)d_in[14]};
    const float* mm_w[2]   = {(const float*)d_in[15], (const float*)d_in[17]};
    const float* mm_b[2]   = {(const float*)d_in[16], (const float*)d_in[18]};

    const size_t HPE = (size_t)BATCH*64*HW;   // elems per 64-ch plane
    u16* PL = (u16*)d_ws;                     // 12 planes
    u16* P[12];
    for (int i = 0; i < 12; i++) P[i] = PL + (size_t)i*HPE;
    float* sums = (float*)(PL + 12*HPE);      // 2 * 2560 f32
    float* lnc  = sums + 5120;                // 768 f32 LN rowsum constants
    u16* warena = (u16*)(lnc + 768);
    // merged gemm arenas: seg0 = kv_w[0](8192) + q_w[1](4096); seg1 = kv_w[1] + q_w[0]
    const int WG[2] = {0, 12288};
    const int WMA[2] = {24576, 40960}, WMB[2] = {32768, 49152};
    const int WEFF[2] = {57344, 73728};

    size_t need = 12*HPE*2 + (5120+768)*4 + 90112*2;
    if (ws_size < need) return;

    SetupArgs S{};
    int nj = 0;
    auto add = [&](const float* s, u16* d, int n, const float* cs){ S.j[nj] = {s, d, n, cs}; nj++; };
    add(kv_w[0], warena + WG[0],        8192, ln_w);
    add(q_w[1],  warena + WG[0] + 8192, 4096, ln_w);
    add(kv_w[1], warena + WG[1],        8192, ln_w);
    add(q_w[0],  warena + WG[1] + 8192, 4096, ln_w);
    for (int br = 0; br < 2; br++){
        add(mm_w[br],        warena + WMA[br],        4096, nullptr);  // W0 -> rows 0-63
        add(mm_w[br]+8192,   warena + WMA[br] + 4096, 4096, nullptr);  // W2 -> rows 64-127
        add(mm_w[br]+4096,   warena + WMB[br],        4096, nullptr);  // W1 -> rows 0-63
        add(mm_w[br]+12288,  warena + WMB[br] + 4096, 4096, nullptr);  // W3 -> rows 64-127
    }
    S.kvw[0] = kv_w[0]; S.kvw[1] = kv_w[1];
    S.qw[0]  = q_w[0];  S.qw[1]  = q_w[1];
    S.lnw = ln_w; S.lnb = ln_b; S.sums = sums; S.lnc = lnc;
    setup_kernel<<<15, 256, 0, stream>>>(S);

    const int GT = NPIX/256;     // 1024 gemm tiles per seg (256 px each)

    // merged LN-GEMM: seg0 x -> P0(k0),P1(v0),P5(q1); seg1 y -> P2(k1),P3(v1),P4(q0)
    GemmMerged GK{};
    GK.in[0] = x; GK.in[1] = y;
    GK.wa[0] = warena + WG[0]; GK.wa[1] = warena + WG[1];
    GK.rs[0] = lnc;        GK.rb[0] = lnc + 192;
    GK.rs[1] = lnc + 384;  GK.rb[1] = lnc + 576;
    GK.out0[0] = P[0]; GK.out1[0] = P[1]; GK.out2[0] = P[5];
    GK.out0[1] = P[2]; GK.out1[1] = P[3]; GK.out2[1] = P[4];
    gemmln_kernel<<<2*GT, 256, 0, stream>>>(GK);

    // depthwise, all 6 planes in one dispatch:
    // br0: P0->P6 (k), P1->P7 (v), P4->P8 (q); br1: P2->P9, P3->P10, P5->P11
    Dw6 D{};
    D.in[0] = P[0];  D.out[0] = P[6];  D.w[0] = kvdw_w[0]; D.choff[0] = 0;
    D.in[1] = P[1];  D.out[1] = P[7];  D.w[1] = kvdw_w[0]; D.choff[1] = 64;
    D.in[2] = P[4];  D.out[2] = P[8];  D.w[2] = qdw_w[0];  D.choff[2] = 0;
    D.in[3] = P[2];  D.out[3] = P[9];  D.w[3] = kvdw_w[1]; D.choff[3] = 0;
    D.in[4] = P[3];  D.out[4] = P[10]; D.w[4] = kvdw_w[1]; D.choff[4] = 64;
    D.in[5] = P[5];  D.out[5] = P[11]; D.w[5] = qdw_w[1];  D.choff[5] = 0;
    dw6_kernel<<<6*8192, 256, 0, stream>>>(D);

    // attention stats both branches
    AttnDual AD{};
    AD.q[0] = P[8];  AD.k[0] = P[6];
    AD.q[1] = P[11]; AD.k[1] = P[9];
    AD.sums = sums;
    attn_part_kernel<<<2*BATCH*8*NSL, 256, 0, stream>>>(AD);

    // softmax + Weff both branches
    WeffDual WD{};
    WD.sums = sums; WD.temp = temp;
    WD.po[0] = po_w[0]; WD.po[1] = po_w[1];
    WD.weff[0] = warena + WEFF[0]; WD.weff[1] = warena + WEFF[1];
    weff_kernel<<<2*BATCH, 64, 0, stream>>>(WD);

    // fused modulation + final both branches
    float* outp = (float*)d_out;
    ModFinal M{};
    M.in[0] = x; M.in[1] = y;
    M.wa[0] = warena + WMA[0]; M.wa[1] = warena + WMA[1];
    M.wb[0] = warena + WMB[0]; M.wb[1] = warena + WMB[1];
    M.b0[0] = mm_b[0];       M.b0[1] = mm_b[1];
    M.b2[0] = mm_b[0] + 128; M.b2[1] = mm_b[1] + 128;
    M.b1[0] = mm_b[0] + 64;  M.b1[1] = mm_b[1] + 64;
    M.b3[0] = mm_b[0] + 192; M.b3[1] = mm_b[1] + 192;
    M.wf[0] = warena + WEFF[0]; M.wf[1] = warena + WEFF[1];
    M.v[0] = P[7]; M.v[1] = P[10];
    M.resid[0] = y; M.resid[1] = x;
    M.out[0] = outp; M.out[1] = outp + HPE;
    modfinal_kernel<<<2*GT, 256, 0, stream>>>(M);
}